// Round 1
// baseline (5822.544 us; speedup 1.0000x reference)
//
#include <hip/hip_runtime.h>
#include <hip/hip_bf16.h>

typedef __attribute__((ext_vector_type(8))) short short8;
typedef __attribute__((ext_vector_type(4))) short short4v;
typedef __attribute__((ext_vector_type(4))) float f32x4;

#define TM 32          // nodes per block
#define SX 136         // lds row stride (bf16) for X   (128 + 8 pad)
#define S1 264         // lds row stride for H1         (256 + 8 pad)
#define S2 520         // lds row stride for H2         (512 + 8 pad)

__device__ __forceinline__ short f2bf(float x) {
    union { float f; unsigned u; } v; v.f = x;
    unsigned r = v.u + 0x7fffu + ((v.u >> 16) & 1u);
    return (short)(r >> 16);
}

// ---- weight prep: f32 [k][n] -> bf16 transposed [n][k] ----
__global__ __launch_bounds__(256) void prep_weights(
        const float* __restrict__ W1, const float* __restrict__ W2,
        const float* __restrict__ W3,
        short* __restrict__ W1t, short* __restrict__ W2t, short* __restrict__ W3t) {
    int i = blockIdx.x * 256 + threadIdx.x;
    if (i < 32768) {                       // W1: 128x256 -> W1t: 256x128
        int n = i >> 7, k = i & 127;
        W1t[i] = f2bf(W1[k * 256 + n]);
    } else if (i < 32768 + 131072) {       // W2: 256x512 -> W2t: 512x256
        int j = i - 32768;
        int n = j >> 8, k = j & 255;
        W2t[j] = f2bf(W2[k * 512 + n]);
    } else if (i < 229376) {               // W3: 512x128 -> W3t: 128x512
        int j = i - 163840;
        int n = j >> 9, k = j & 511;
        W3t[j] = f2bf(W3[k * 128 + n]);
    }
}

// ---- zero the agg half of out (harness poisons d_out with 0xAA) ----
__global__ __launch_bounds__(256) void zero_agg(float* __restrict__ out, int n_nodes) {
    int i = blockIdx.x * 256 + threadIdx.x;
    int total = n_nodes * 32;              // float4 slots per agg row
    for (; i < total; i += gridDim.x * 256) {
        int n = i >> 5, q = i & 31;
        *(float4*)&out[(long)n * 256 + 128 + q * 4] = make_float4(0.f, 0.f, 0.f, 0.f);
    }
}

// ---- fused 3-layer MLP, bf16 MFMA, 32 nodes per block ----
// out[node][0:128] = h(node); agg half untouched here.
__global__ __launch_bounds__(256) void mlp_kernel(
        const float* __restrict__ X,
        const float* __restrict__ b1f, const float* __restrict__ b2f,
        const float* __restrict__ b3f,
        const short* __restrict__ W1t, const short* __restrict__ W2t,
        const short* __restrict__ W3t,
        float* __restrict__ out, int n_nodes) {
    // LDS: H2 [32][520] at 0, H1 [32][264] after; X [32][136] aliases H2 (X dead
    // before layer2 writes H2).
    __shared__ short lds[TM * S2 + TM * S1];   // 25088 shorts = 50176 B
    short* ldsH2 = lds;
    short* ldsH1 = lds + TM * S2;
    short* ldsX  = lds;

    const int tid  = threadIdx.x;
    const int wave = tid >> 6;
    const int lane = tid & 63;
    const int ln   = lane & 15;
    const int quad = lane >> 4;
    const int rh   = wave & 1;     // row half (16 rows each)
    const int ch   = wave >> 1;    // col half
    const int r0   = rh * 16;
    const long node0 = (long)blockIdx.x * TM;

    // ---- stage X -> LDS (f32 -> bf16) ----
    for (int i = tid; i < TM * 32; i += 256) {    // 32 rows x 32 float4
        int r = i >> 5, c4 = i & 31;
        long node = node0 + r;
        float4 v = make_float4(0.f, 0.f, 0.f, 0.f);
        if (node < n_nodes) v = *(const float4*)&X[node * 128 + c4 * 4];
        short4v s;
        s.x = f2bf(v.x); s.y = f2bf(v.y); s.z = f2bf(v.z); s.w = f2bf(v.w);
        *(short4v*)&ldsX[r * SX + c4 * 4] = s;
    }
    __syncthreads();

    // ---- layer 1: [32x128] @ [128x256], wave does 16 rows x 128 cols ----
    {
        short8 a[4];
#pragma unroll
        for (int k = 0; k < 4; ++k)
            a[k] = *(const short8*)&ldsX[(r0 + ln) * SX + k * 32 + quad * 8];
#pragma unroll
        for (int nt = 0; nt < 8; ++nt) {
            int n = ch * 128 + nt * 16 + ln;
            const short* bp = &W1t[n * 128 + quad * 8];
            f32x4 c = {0.f, 0.f, 0.f, 0.f};
#pragma unroll
            for (int k = 0; k < 4; ++k) {
                short8 b = *(const short8*)(bp + k * 32);
                c = __builtin_amdgcn_mfma_f32_16x16x32_bf16(a[k], b, c, 0, 0, 0);
            }
            float bias = b1f[n];
#pragma unroll
            for (int rr = 0; rr < 4; ++rr) {
                float h = c[rr] + bias;
                h = h > 0.f ? h : 0.f;
                ldsH1[(r0 + quad * 4 + rr) * S1 + n] = f2bf(h);
            }
        }
    }
    __syncthreads();

    // ---- layer 2: [32x256] @ [256x512], wave does 16 rows x 256 cols ----
    {
        short8 a[8];
#pragma unroll
        for (int k = 0; k < 8; ++k)
            a[k] = *(const short8*)&ldsH1[(r0 + ln) * S1 + k * 32 + quad * 8];
#pragma unroll
        for (int nt = 0; nt < 16; ++nt) {
            int n = ch * 256 + nt * 16 + ln;
            const short* bp = &W2t[n * 256 + quad * 8];
            f32x4 c = {0.f, 0.f, 0.f, 0.f};
#pragma unroll
            for (int k = 0; k < 8; ++k) {
                short8 b = *(const short8*)(bp + k * 32);
                c = __builtin_amdgcn_mfma_f32_16x16x32_bf16(a[k], b, c, 0, 0, 0);
            }
            float bias = b2f[n];
#pragma unroll
            for (int rr = 0; rr < 4; ++rr) {
                float h = c[rr] + bias;
                h = h > 0.f ? h : 0.f;
                ldsH2[(r0 + quad * 4 + rr) * S2 + n] = f2bf(h);
            }
        }
    }
    __syncthreads();

    // ---- layer 3: [32x512] @ [512x128], wave does 16 rows x 64 cols ----
    {
        short8 a[16];
#pragma unroll
        for (int k = 0; k < 16; ++k)
            a[k] = *(const short8*)&ldsH2[(r0 + ln) * S2 + k * 32 + quad * 8];
#pragma unroll
        for (int nt = 0; nt < 4; ++nt) {
            int n = ch * 64 + nt * 16 + ln;
            const short* bp = &W3t[n * 512 + quad * 8];
            f32x4 c = {0.f, 0.f, 0.f, 0.f};
#pragma unroll
            for (int k = 0; k < 16; ++k) {
                short8 b = *(const short8*)(bp + k * 32);
                c = __builtin_amdgcn_mfma_f32_16x16x32_bf16(a[k], b, c, 0, 0, 0);
            }
            float bias = b3f[n];
#pragma unroll
            for (int rr = 0; rr < 4; ++rr) {
                long node = node0 + r0 + quad * 4 + rr;
                if (node < n_nodes) out[node * 256 + n] = c[rr] + bias;
            }
        }
    }
}

// ---- edge aggregation: agg[dst] += h[src], 32 lanes per edge ----
__global__ __launch_bounds__(256) void edge_agg(
        const int* __restrict__ src, const int* __restrict__ dst,
        float* __restrict__ out, int n_edges) {
    int e = blockIdx.x * 8 + (threadIdx.x >> 5);
    if (e >= n_edges) return;
    int l = threadIdx.x & 31;
    long s = src[e];
    long d = dst[e];
    const float4 v = *(const float4*)&out[s * 256 + l * 4];
    float* p = &out[d * 256 + 128 + l * 4];
    unsafeAtomicAdd(p + 0, v.x);
    unsafeAtomicAdd(p + 1, v.y);
    unsafeAtomicAdd(p + 2, v.z);
    unsafeAtomicAdd(p + 3, v.w);
}

extern "C" void kernel_launch(void* const* d_in, const int* in_sizes, int n_in,
                              void* d_out, int out_size, void* d_ws, size_t ws_size,
                              hipStream_t stream) {
    const float* X  = (const float*)d_in[0];
    const int*   src = (const int*)d_in[1];
    const int*   dst = (const int*)d_in[2];
    const float* W1 = (const float*)d_in[3];
    const float* b1 = (const float*)d_in[4];
    const float* W2 = (const float*)d_in[5];
    const float* b2 = (const float*)d_in[6];
    const float* W3 = (const float*)d_in[7];
    const float* b3 = (const float*)d_in[8];
    float* out = (float*)d_out;

    const int n_nodes = in_sizes[0] / 128;
    const int n_edges = in_sizes[1];

    short* W1t = (short*)d_ws;            // 32768 bf16
    short* W2t = W1t + 32768;             // 131072 bf16
    short* W3t = W2t + 131072;            // 65536 bf16

    prep_weights<<<896, 256, 0, stream>>>(W1, W2, W3, W1t, W2t, W3t);
    zero_agg<<<3125, 256, 0, stream>>>(out, n_nodes);
    mlp_kernel<<<(n_nodes + TM - 1) / TM, 256, 0, stream>>>(
        X, b1, b2, b3, W1t, W2t, W3t, out, n_nodes);
    edge_agg<<<(n_edges + 7) / 8, 256, 0, stream>>>(src, dst, out, n_edges);
}

// Round 3
// 1081.546 us; speedup vs baseline: 5.3835x; 5.3835x over previous
//
#include <hip/hip_runtime.h>
#include <hip/hip_bf16.h>

typedef __attribute__((ext_vector_type(8))) short short8;
typedef __attribute__((ext_vector_type(4))) short short4v;
typedef __attribute__((ext_vector_type(4))) float f32x4;

#define TM 32          // nodes per block (mlp)
#define SX 136         // lds row stride (bf16) for X   (128 + 8 pad)
#define S1 264         // lds row stride for H1         (256 + 8 pad)
#define S2 520         // lds row stride for H2         (512 + 8 pad)

__device__ __forceinline__ short f2bf(float x) {
    union { float f; unsigned u; } v; v.f = x;
    unsigned r = v.u + 0x7fffu + ((v.u >> 16) & 1u);
    return (short)(r >> 16);
}

// ---- weight prep: f32 [k][n] -> bf16 transposed [n][k] ----
__global__ __launch_bounds__(256) void prep_weights(
        const float* __restrict__ W1, const float* __restrict__ W2,
        const float* __restrict__ W3,
        short* __restrict__ W1t, short* __restrict__ W2t, short* __restrict__ W3t) {
    int i = blockIdx.x * 256 + threadIdx.x;
    if (i < 32768) {                       // W1: 128x256 -> W1t: 256x128
        int n = i >> 7, k = i & 127;
        W1t[i] = f2bf(W1[k * 256 + n]);
    } else if (i < 32768 + 131072) {       // W2: 256x512 -> W2t: 512x256
        int j = i - 32768;
        int n = j >> 8, k = j & 255;
        W2t[j] = f2bf(W2[k * 512 + n]);
    } else if (i < 229376) {               // W3: 512x128 -> W3t: 128x512
        int j = i - 163840;
        int n = j >> 9, k = j & 511;
        W3t[j] = f2bf(W3[k * 128 + n]);
    }
}

// ---- CSR build: histogram over dst (into cursor, pre-zeroed) ----
__global__ __launch_bounds__(256) void hist_kernel(
        const int* __restrict__ dst, int* __restrict__ cursor, int n_edges) {
    int e = blockIdx.x * 256 + threadIdx.x;
    if (e < n_edges) atomicAdd(&cursor[dst[e]], 1);
}

// ---- scan step 1: per-block (256) sums of deg -> part ----
__global__ __launch_bounds__(256) void scan1_kernel(
        const int* __restrict__ deg, int* __restrict__ part, int n) {
    __shared__ int sred[4];
    int tid = threadIdx.x;
    int i = blockIdx.x * 256 + tid;
    int v = (i < n) ? deg[i] : 0;
#pragma unroll
    for (int off = 32; off > 0; off >>= 1) v += __shfl_down(v, off, 64);
    if ((tid & 63) == 0) sred[tid >> 6] = v;
    __syncthreads();
    if (tid == 0) part[blockIdx.x] = sred[0] + sred[1] + sred[2] + sred[3];
}

// ---- scan step 2: single-block exclusive scan of part (nb <= 512) ----
__global__ __launch_bounds__(512) void scan2_kernel(int* __restrict__ part, int nb) {
    __shared__ int s[512];
    int t = threadIdx.x;
    s[t] = (t < nb) ? part[t] : 0;
    __syncthreads();
#pragma unroll
    for (int off = 1; off < 512; off <<= 1) {
        int v = (t >= off) ? s[t - off] : 0;
        __syncthreads();
        s[t] += v;
        __syncthreads();
    }
    if (t < nb) part[t] = (t == 0) ? 0 : s[t - 1];
}

// ---- scan step 3: cursor holds deg on entry; exits as exclusive offsets.
//      offs gets a stable copy (offs[n] = total). ----
__global__ __launch_bounds__(256) void scan3_kernel(
        const int* __restrict__ part, int* __restrict__ cursor,
        int* __restrict__ offs, int n) {
    __shared__ int s[256];
    int t = threadIdx.x;
    int i = blockIdx.x * 256 + t;
    int v = (i < n) ? cursor[i] : 0;
    s[t] = v;
    __syncthreads();
#pragma unroll
    for (int off = 1; off < 256; off <<= 1) {
        int u = (t >= off) ? s[t - off] : 0;
        __syncthreads();
        s[t] += u;
        __syncthreads();
    }
    if (i < n) {
        int base = part[blockIdx.x];
        int ex = base + s[t] - v;
        offs[i] = ex;
        cursor[i] = ex;
        if (i == n - 1) offs[n] = base + s[t];
    }
}

// ---- scatter: edge src ids bucketed by dst ----
__global__ __launch_bounds__(256) void scatter_kernel(
        const int* __restrict__ src, const int* __restrict__ dst,
        int* __restrict__ cursor, int* __restrict__ esrc, int n_edges) {
    int e = blockIdx.x * 256 + threadIdx.x;
    if (e < n_edges) {
        int p = atomicAdd(&cursor[dst[e]], 1);
        esrc[p] = src[e];
    }
}

// ---- fused 3-layer MLP, bf16 MFMA, 32 nodes per block ----
__global__ __launch_bounds__(256) void mlp_kernel(
        const float* __restrict__ X,
        const float* __restrict__ b1f, const float* __restrict__ b2f,
        const float* __restrict__ b3f,
        const short* __restrict__ W1t, const short* __restrict__ W2t,
        const short* __restrict__ W3t,
        float* __restrict__ out, int n_nodes) {
    __shared__ short lds[TM * S2 + TM * S1];   // 50176 B
    short* ldsH2 = lds;
    short* ldsH1 = lds + TM * S2;
    short* ldsX  = lds;

    const int tid  = threadIdx.x;
    const int wave = tid >> 6;
    const int lane = tid & 63;
    const int ln   = lane & 15;
    const int quad = lane >> 4;
    const int rh   = wave & 1;
    const int ch   = wave >> 1;
    const int r0   = rh * 16;
    const long node0 = (long)blockIdx.x * TM;

    for (int i = tid; i < TM * 32; i += 256) {
        int r = i >> 5, c4 = i & 31;
        long node = node0 + r;
        float4 v = make_float4(0.f, 0.f, 0.f, 0.f);
        if (node < n_nodes) v = *(const float4*)&X[node * 128 + c4 * 4];
        short4v s;
        s.x = f2bf(v.x); s.y = f2bf(v.y); s.z = f2bf(v.z); s.w = f2bf(v.w);
        *(short4v*)&ldsX[r * SX + c4 * 4] = s;
    }
    __syncthreads();

    {   // layer 1: [32x128] @ [128x256]
        short8 a[4];
#pragma unroll
        for (int k = 0; k < 4; ++k)
            a[k] = *(const short8*)&ldsX[(r0 + ln) * SX + k * 32 + quad * 8];
#pragma unroll
        for (int nt = 0; nt < 8; ++nt) {
            int n = ch * 128 + nt * 16 + ln;
            const short* bp = &W1t[n * 128 + quad * 8];
            f32x4 c = {0.f, 0.f, 0.f, 0.f};
#pragma unroll
            for (int k = 0; k < 4; ++k) {
                short8 b = *(const short8*)(bp + k * 32);
                c = __builtin_amdgcn_mfma_f32_16x16x32_bf16(a[k], b, c, 0, 0, 0);
            }
            float bias = b1f[n];
#pragma unroll
            for (int rr = 0; rr < 4; ++rr) {
                float h = c[rr] + bias;
                h = h > 0.f ? h : 0.f;
                ldsH1[(r0 + quad * 4 + rr) * S1 + n] = f2bf(h);
            }
        }
    }
    __syncthreads();

    {   // layer 2: [32x256] @ [256x512]
        short8 a[8];
#pragma unroll
        for (int k = 0; k < 8; ++k)
            a[k] = *(const short8*)&ldsH1[(r0 + ln) * S1 + k * 32 + quad * 8];
#pragma unroll
        for (int nt = 0; nt < 16; ++nt) {
            int n = ch * 256 + nt * 16 + ln;
            const short* bp = &W2t[n * 256 + quad * 8];
            f32x4 c = {0.f, 0.f, 0.f, 0.f};
#pragma unroll
            for (int k = 0; k < 8; ++k) {
                short8 b = *(const short8*)(bp + k * 32);
                c = __builtin_amdgcn_mfma_f32_16x16x32_bf16(a[k], b, c, 0, 0, 0);
            }
            float bias = b2f[n];
#pragma unroll
            for (int rr = 0; rr < 4; ++rr) {
                float h = c[rr] + bias;
                h = h > 0.f ? h : 0.f;
                ldsH2[(r0 + quad * 4 + rr) * S2 + n] = f2bf(h);
            }
        }
    }
    __syncthreads();

    {   // layer 3: [32x512] @ [512x128]
        short8 a[16];
#pragma unroll
        for (int k = 0; k < 16; ++k)
            a[k] = *(const short8*)&ldsH2[(r0 + ln) * S2 + k * 32 + quad * 8];
#pragma unroll
        for (int nt = 0; nt < 4; ++nt) {
            int n = ch * 64 + nt * 16 + ln;
            const short* bp = &W3t[n * 512 + quad * 8];
            f32x4 c = {0.f, 0.f, 0.f, 0.f};
#pragma unroll
            for (int k = 0; k < 16; ++k) {
                short8 b = *(const short8*)(bp + k * 32);
                c = __builtin_amdgcn_mfma_f32_16x16x32_bf16(a[k], b, c, 0, 0, 0);
            }
            float bias = b3f[n];
#pragma unroll
            for (int rr = 0; rr < 4; ++rr) {
                long node = node0 + r0 + quad * 4 + rr;
                if (node < n_nodes) out[node * 256 + n] = c[rr] + bias;
            }
        }
    }
}

// ---- aggregation: one wave per node, no atomics, no shfl ----
// Lane owns a float2 feature chunk (64 lanes x 8B = full 128-f32 row).
// Edge indices loaded directly, 8-deep software pipeline for MLP-in-flight.
__global__ __launch_bounds__(256) void agg_kernel(
        const int* __restrict__ esrc, const int* __restrict__ offs,
        float* __restrict__ out, int n_nodes) {
    int node = blockIdx.x * 4 + (threadIdx.x >> 6);
    if (node >= n_nodes) return;
    const int l2 = (threadIdx.x & 63) * 2;
    const int s0 = offs[node];
    const int s1 = offs[node + 1];
    float ax = 0.f, ay = 0.f;
    int j = s0;
    for (; j + 8 <= s1; j += 8) {
        int s[8];
#pragma unroll
        for (int u = 0; u < 8; ++u) s[u] = esrc[j + u];
        float2 v[8];
#pragma unroll
        for (int u = 0; u < 8; ++u) v[u] = *(const float2*)&out[(long)s[u] * 256 + l2];
#pragma unroll
        for (int u = 0; u < 8; ++u) { ax += v[u].x; ay += v[u].y; }
    }
    for (; j < s1; ++j) {
        float2 v = *(const float2*)&out[(long)esrc[j] * 256 + l2];
        ax += v.x; ay += v.y;
    }
    *(float2*)&out[(long)node * 256 + 128 + l2] = make_float2(ax, ay);
}

// ---- fallback path (small ws): zero agg + atomic scatter-add ----
__global__ __launch_bounds__(256) void zero_agg(float* __restrict__ out, int n_nodes) {
    int i = blockIdx.x * 256 + threadIdx.x;
    int total = n_nodes * 32;
    for (; i < total; i += gridDim.x * 256) {
        int n = i >> 5, q = i & 31;
        *(float4*)&out[(long)n * 256 + 128 + q * 4] = make_float4(0.f, 0.f, 0.f, 0.f);
    }
}

__global__ __launch_bounds__(256) void edge_agg(
        const int* __restrict__ src, const int* __restrict__ dst,
        float* __restrict__ out, int n_edges) {
    int e = blockIdx.x * 8 + (threadIdx.x >> 5);
    if (e >= n_edges) return;
    int l = threadIdx.x & 31;
    long s = src[e];
    long d = dst[e];
    const float4 v = *(const float4*)&out[s * 256 + l * 4];
    float* p = &out[d * 256 + 128 + l * 4];
    unsafeAtomicAdd(p + 0, v.x);
    unsafeAtomicAdd(p + 1, v.y);
    unsafeAtomicAdd(p + 2, v.z);
    unsafeAtomicAdd(p + 3, v.w);
}

extern "C" void kernel_launch(void* const* d_in, const int* in_sizes, int n_in,
                              void* d_out, int out_size, void* d_ws, size_t ws_size,
                              hipStream_t stream) {
    const float* X   = (const float*)d_in[0];
    const int*   src = (const int*)d_in[1];
    const int*   dst = (const int*)d_in[2];
    const float* W1  = (const float*)d_in[3];
    const float* b1  = (const float*)d_in[4];
    const float* W2  = (const float*)d_in[5];
    const float* b2  = (const float*)d_in[6];
    const float* W3  = (const float*)d_in[7];
    const float* b3  = (const float*)d_in[8];
    float* out = (float*)d_out;

    const int n_nodes = in_sizes[0] / 128;
    const int n_edges = in_sizes[1];
    const int NB = (n_nodes + 255) / 256;

    char* ws = (char*)d_ws;
    short* W1t = (short*)ws;              // 32768 bf16
    short* W2t = W1t + 32768;             // 131072 bf16
    short* W3t = W2t + 131072;            // 65536 bf16  (total 448 KiB, proven safe)

    // CSR scratch (beyond the 512 KiB weight region)
    int* cursor = (int*)(ws + 512 * 1024);     // n_nodes (deg -> offsets -> cursors)
    int* offs   = cursor + n_nodes;            // n_nodes + 1
    int* part   = offs + n_nodes + 1;          // 512 block sums
    int* esrc   = part + 512;                  // n_edges
    size_t need = 512 * 1024 +
                  sizeof(int) * ((size_t)2 * n_nodes + 1 + 512 + (size_t)n_edges);
    const bool use_csr = (ws_size >= need) && (NB <= 512);

    prep_weights<<<896, 256, 0, stream>>>(W1, W2, W3, W1t, W2t, W3t);
    mlp_kernel<<<(n_nodes + TM - 1) / TM, 256, 0, stream>>>(
        X, b1, b2, b3, W1t, W2t, W3t, out, n_nodes);

    if (use_csr) {
        hipMemsetAsync(cursor, 0, (size_t)n_nodes * 4, stream);
        hist_kernel<<<(n_edges + 255) / 256, 256, 0, stream>>>(dst, cursor, n_edges);
        scan1_kernel<<<NB, 256, 0, stream>>>(cursor, part, n_nodes);
        scan2_kernel<<<1, 512, 0, stream>>>(part, NB);
        scan3_kernel<<<NB, 256, 0, stream>>>(part, cursor, offs, n_nodes);
        scatter_kernel<<<(n_edges + 255) / 256, 256, 0, stream>>>(src, dst, cursor, esrc, n_edges);
        agg_kernel<<<(n_nodes + 3) / 4, 256, 0, stream>>>(esrc, offs, out, n_nodes);
    } else {
        zero_agg<<<3125, 256, 0, stream>>>(out, n_nodes);
        edge_agg<<<(n_edges + 7) / 8, 256, 0, stream>>>(src, dst, out, n_edges);
    }
}

// Round 4
// 879.071 us; speedup vs baseline: 6.6235x; 1.2303x over previous
//
#include <hip/hip_runtime.h>
#include <hip/hip_bf16.h>

typedef __attribute__((ext_vector_type(8))) short short8;
typedef __attribute__((ext_vector_type(4))) short short4v;
typedef __attribute__((ext_vector_type(4))) float f32x4;

#define TM 64          // nodes per block (mlp)
#define SX 136         // lds row stride (bf16) for X / H2 chunk (128 + 8 pad)
#define S1 264         // lds row stride for H1              (256 + 8 pad)

__device__ __forceinline__ short f2bf(float x) {
    union { float f; unsigned u; } v; v.f = x;
    unsigned r = v.u + 0x7fffu + ((v.u >> 16) & 1u);
    return (short)(r >> 16);
}

// ---- weight prep: f32 [k][n] -> bf16 transposed [n][k] ----
__global__ __launch_bounds__(256) void prep_weights(
        const float* __restrict__ W1, const float* __restrict__ W2,
        const float* __restrict__ W3,
        short* __restrict__ W1t, short* __restrict__ W2t, short* __restrict__ W3t) {
    int i = blockIdx.x * 256 + threadIdx.x;
    if (i < 32768) {                       // W1: 128x256 -> W1t: 256x128
        int n = i >> 7, k = i & 127;
        W1t[i] = f2bf(W1[k * 256 + n]);
    } else if (i < 32768 + 131072) {       // W2: 256x512 -> W2t: 512x256
        int j = i - 32768;
        int n = j >> 8, k = j & 255;
        W2t[j] = f2bf(W2[k * 512 + n]);
    } else if (i < 229376) {               // W3: 512x128 -> W3t: 128x512
        int j = i - 163840;
        int n = j >> 9, k = j & 511;
        W3t[j] = f2bf(W3[k * 128 + n]);
    }
}

// ---- CSR build: histogram over dst (into cursor, pre-zeroed) ----
__global__ __launch_bounds__(256) void hist_kernel(
        const int* __restrict__ dst, int* __restrict__ cursor, int n_edges) {
    int e = blockIdx.x * 256 + threadIdx.x;
    if (e < n_edges) atomicAdd(&cursor[dst[e]], 1);
}

// ---- scan step 1: per-block (256) sums of deg -> part ----
__global__ __launch_bounds__(256) void scan1_kernel(
        const int* __restrict__ deg, int* __restrict__ part, int n) {
    __shared__ int sred[4];
    int tid = threadIdx.x;
    int i = blockIdx.x * 256 + tid;
    int v = (i < n) ? deg[i] : 0;
#pragma unroll
    for (int off = 32; off > 0; off >>= 1) v += __shfl_down(v, off, 64);
    if ((tid & 63) == 0) sred[tid >> 6] = v;
    __syncthreads();
    if (tid == 0) part[blockIdx.x] = sred[0] + sred[1] + sred[2] + sred[3];
}

// ---- scan step 2: single-block exclusive scan of part (nb <= 512) ----
__global__ __launch_bounds__(512) void scan2_kernel(int* __restrict__ part, int nb) {
    __shared__ int s[512];
    int t = threadIdx.x;
    s[t] = (t < nb) ? part[t] : 0;
    __syncthreads();
#pragma unroll
    for (int off = 1; off < 512; off <<= 1) {
        int v = (t >= off) ? s[t - off] : 0;
        __syncthreads();
        s[t] += v;
        __syncthreads();
    }
    if (t < nb) part[t] = (t == 0) ? 0 : s[t - 1];
}

// ---- scan step 3: cursor holds deg on entry; exits as exclusive offsets ----
__global__ __launch_bounds__(256) void scan3_kernel(
        const int* __restrict__ part, int* __restrict__ cursor,
        int* __restrict__ offs, int n) {
    __shared__ int s[256];
    int t = threadIdx.x;
    int i = blockIdx.x * 256 + t;
    int v = (i < n) ? cursor[i] : 0;
    s[t] = v;
    __syncthreads();
#pragma unroll
    for (int off = 1; off < 256; off <<= 1) {
        int u = (t >= off) ? s[t - off] : 0;
        __syncthreads();
        s[t] += u;
        __syncthreads();
    }
    if (i < n) {
        int base = part[blockIdx.x];
        int ex = base + s[t] - v;
        offs[i] = ex;
        cursor[i] = ex;
        if (i == n - 1) offs[n] = base + s[t];
    }
}

// ---- scatter: edge src ids bucketed by dst ----
__global__ __launch_bounds__(256) void scatter_kernel(
        const int* __restrict__ src, const int* __restrict__ dst,
        int* __restrict__ cursor, int* __restrict__ esrc, int n_edges) {
    int e = blockIdx.x * 256 + threadIdx.x;
    if (e < n_edges) {
        int p = atomicAdd(&cursor[dst[e]], 1);
        esrc[p] = src[e];
    }
}

// ---- fused 3-layer MLP, bf16 MFMA, 64 nodes/block, 4 waves by out-col ----
// Each wave owns 4 m-tiles -> every B fragment feeds 4 MFMAs (was 1).
// Layer3 fused into layer2 via 128-col H2 chunks held in LDS (aliases X).
__global__ __launch_bounds__(256) void mlp_kernel(
        const float* __restrict__ X,
        const float* __restrict__ b1f, const float* __restrict__ b2f,
        const float* __restrict__ b3f,
        const short* __restrict__ W1t, const short* __restrict__ W2t,
        const short* __restrict__ W3t,
        float* __restrict__ out, int n_nodes) {
    __shared__ short lds[TM * S1 + TM * SX];   // H1 (33792B) + X/H2chunk (17408B)
    short* ldsH1 = lds;
    short* ldsX  = lds + TM * S1;   // X aliases H2 chunk (X dead after layer1)
    short* ldsH2 = ldsX;

    const int tid  = threadIdx.x;
    const int ch   = tid >> 6;      // wave = output-column group
    const int lane = tid & 63;
    const int ln   = lane & 15;
    const int quad = lane >> 4;
    const long node0 = (long)blockIdx.x * TM;

    // ---- stage X -> LDS (f32 -> bf16): 64 rows x 32 float4 ----
    for (int i = tid; i < TM * 32; i += 256) {
        int r = i >> 5, c4 = i & 31;
        long node = node0 + r;
        float4 v = make_float4(0.f, 0.f, 0.f, 0.f);
        if (node < n_nodes) v = *(const float4*)&X[node * 128 + c4 * 4];
        short4v s;
        s.x = f2bf(v.x); s.y = f2bf(v.y); s.z = f2bf(v.z); s.w = f2bf(v.w);
        *(short4v*)&ldsX[r * SX + c4 * 4] = s;
    }
    __syncthreads();

    // ---- layer 1: H1[64x256] = relu(X @ W1 + b1); wave cols ch*64..+64 ----
#pragma unroll
    for (int nt = 0; nt < 4; ++nt) {
        int n = ch * 64 + nt * 16 + ln;
        const short* bp = &W1t[n * 128 + quad * 8];
        short8 b[4];
#pragma unroll
        for (int kk = 0; kk < 4; ++kk) b[kk] = *(const short8*)(bp + kk * 32);
        float bias = b1f[n];
#pragma unroll
        for (int m = 0; m < 4; ++m) {
            f32x4 c = {0.f, 0.f, 0.f, 0.f};
#pragma unroll
            for (int kk = 0; kk < 4; ++kk) {
                short8 a = *(const short8*)&ldsX[(m * 16 + ln) * SX + kk * 32 + quad * 8];
                c = __builtin_amdgcn_mfma_f32_16x16x32_bf16(a, b[kk], c, 0, 0, 0);
            }
#pragma unroll
            for (int rr = 0; rr < 4; ++rr) {
                float h = c[rr] + bias;
                h = h > 0.f ? h : 0.f;
                ldsH1[(m * 16 + quad * 4 + rr) * S1 + n] = f2bf(h);
            }
        }
    }
    __syncthreads();   // H1 complete; X region now free for H2 chunks

    // ---- layers 2+3 fused over 4 chunks of 128 H2 cols ----
    f32x4 acc3[4][2] = {};
#pragma unroll 1
    for (int cc = 0; cc < 4; ++cc) {
        // layer 2 part: H2[:, cc*128..+128] = relu(H1 @ W2[:,chunk] + b2)
#pragma unroll
        for (int nt = 0; nt < 2; ++nt) {
            int n2 = cc * 128 + ch * 32 + nt * 16 + ln;
            const short* bp = &W2t[n2 * 256 + quad * 8];
            short8 b[8];
#pragma unroll
            for (int kk = 0; kk < 8; ++kk) b[kk] = *(const short8*)(bp + kk * 32);
            float bias = b2f[n2];
            int nl = ch * 32 + nt * 16 + ln;   // col within chunk
#pragma unroll
            for (int m = 0; m < 4; ++m) {
                f32x4 c = {0.f, 0.f, 0.f, 0.f};
#pragma unroll
                for (int kk = 0; kk < 8; ++kk) {
                    short8 a = *(const short8*)&ldsH1[(m * 16 + ln) * S1 + kk * 32 + quad * 8];
                    c = __builtin_amdgcn_mfma_f32_16x16x32_bf16(a, b[kk], c, 0, 0, 0);
                }
#pragma unroll
                for (int rr = 0; rr < 4; ++rr) {
                    float h = c[rr] + bias;
                    h = h > 0.f ? h : 0.f;
                    ldsH2[(m * 16 + quad * 4 + rr) * SX + nl] = f2bf(h);
                }
            }
        }
        __syncthreads();   // chunk fully written

        // layer 3 part: acc3 += H2chunk @ W3[chunk rows, :]
#pragma unroll
        for (int nt = 0; nt < 2; ++nt) {
            int n3 = ch * 32 + nt * 16 + ln;
            const short* bp = &W3t[n3 * 512 + cc * 128 + quad * 8];
            short8 b[4];
#pragma unroll
            for (int kk = 0; kk < 4; ++kk) b[kk] = *(const short8*)(bp + kk * 32);
#pragma unroll
            for (int m = 0; m < 4; ++m) {
#pragma unroll
                for (int kk = 0; kk < 4; ++kk) {
                    short8 a = *(const short8*)&ldsH2[(m * 16 + ln) * SX + kk * 32 + quad * 8];
                    acc3[m][nt] = __builtin_amdgcn_mfma_f32_16x16x32_bf16(a, b[kk], acc3[m][nt], 0, 0, 0);
                }
            }
        }
        __syncthreads();   // chunk consumed; safe to overwrite next iter
    }

    // ---- epilogue: out[node][n3] = acc3 + b3 ----
#pragma unroll
    for (int nt = 0; nt < 2; ++nt) {
        int n3 = ch * 32 + nt * 16 + ln;
        float bias = b3f[n3];
#pragma unroll
        for (int m = 0; m < 4; ++m) {
#pragma unroll
            for (int rr = 0; rr < 4; ++rr) {
                long node = node0 + m * 16 + quad * 4 + rr;
                if (node < n_nodes) out[node * 256 + n3] = acc3[m][nt][rr] + bias;
            }
        }
    }
}

// ---- aggregation: one wave per node, no atomics, no shfl ----
__global__ __launch_bounds__(256) void agg_kernel(
        const int* __restrict__ esrc, const int* __restrict__ offs,
        float* __restrict__ out, int n_nodes) {
    int node = blockIdx.x * 4 + (threadIdx.x >> 6);
    if (node >= n_nodes) return;
    const int l2 = (threadIdx.x & 63) * 2;
    const int s0 = offs[node];
    const int s1 = offs[node + 1];
    float ax = 0.f, ay = 0.f;
    int j = s0;
    for (; j + 8 <= s1; j += 8) {
        int s[8];
#pragma unroll
        for (int u = 0; u < 8; ++u) s[u] = esrc[j + u];
        float2 v[8];
#pragma unroll
        for (int u = 0; u < 8; ++u) v[u] = *(const float2*)&out[(long)s[u] * 256 + l2];
#pragma unroll
        for (int u = 0; u < 8; ++u) { ax += v[u].x; ay += v[u].y; }
    }
    for (; j < s1; ++j) {
        float2 v = *(const float2*)&out[(long)esrc[j] * 256 + l2];
        ax += v.x; ay += v.y;
    }
    *(float2*)&out[(long)node * 256 + 128 + l2] = make_float2(ax, ay);
}

// ---- fallback path (small ws): zero agg + atomic scatter-add ----
__global__ __launch_bounds__(256) void zero_agg(float* __restrict__ out, int n_nodes) {
    int i = blockIdx.x * 256 + threadIdx.x;
    int total = n_nodes * 32;
    for (; i < total; i += gridDim.x * 256) {
        int n = i >> 5, q = i & 31;
        *(float4*)&out[(long)n * 256 + 128 + q * 4] = make_float4(0.f, 0.f, 0.f, 0.f);
    }
}

__global__ __launch_bounds__(256) void edge_agg(
        const int* __restrict__ src, const int* __restrict__ dst,
        float* __restrict__ out, int n_edges) {
    int e = blockIdx.x * 8 + (threadIdx.x >> 5);
    if (e >= n_edges) return;
    int l = threadIdx.x & 31;
    long s = src[e];
    long d = dst[e];
    const float4 v = *(const float4*)&out[s * 256 + l * 4];
    float* p = &out[d * 256 + 128 + l * 4];
    unsafeAtomicAdd(p + 0, v.x);
    unsafeAtomicAdd(p + 1, v.y);
    unsafeAtomicAdd(p + 2, v.z);
    unsafeAtomicAdd(p + 3, v.w);
}

extern "C" void kernel_launch(void* const* d_in, const int* in_sizes, int n_in,
                              void* d_out, int out_size, void* d_ws, size_t ws_size,
                              hipStream_t stream) {
    const float* X   = (const float*)d_in[0];
    const int*   src = (const int*)d_in[1];
    const int*   dst = (const int*)d_in[2];
    const float* W1  = (const float*)d_in[3];
    const float* b1  = (const float*)d_in[4];
    const float* W2  = (const float*)d_in[5];
    const float* b2  = (const float*)d_in[6];
    const float* W3  = (const float*)d_in[7];
    const float* b3  = (const float*)d_in[8];
    float* out = (float*)d_out;

    const int n_nodes = in_sizes[0] / 128;
    const int n_edges = in_sizes[1];
    const int NB = (n_nodes + 255) / 256;

    char* ws = (char*)d_ws;
    short* W1t = (short*)ws;              // 32768 bf16
    short* W2t = W1t + 32768;             // 131072 bf16
    short* W3t = W2t + 131072;            // 65536 bf16  (total 448 KiB)

    int* cursor = (int*)(ws + 512 * 1024);     // n_nodes (deg -> offsets -> cursors)
    int* offs   = cursor + n_nodes;            // n_nodes + 1
    int* part   = offs + n_nodes + 1;          // 512 block sums
    int* esrc   = part + 512;                  // n_edges
    size_t need = 512 * 1024 +
                  sizeof(int) * ((size_t)2 * n_nodes + 1 + 512 + (size_t)n_edges);
    const bool use_csr = (ws_size >= need) && (NB <= 512);

    prep_weights<<<896, 256, 0, stream>>>(W1, W2, W3, W1t, W2t, W3t);
    mlp_kernel<<<(n_nodes + TM - 1) / TM, 256, 0, stream>>>(
        X, b1, b2, b3, W1t, W2t, W3t, out, n_nodes);

    if (use_csr) {
        hipMemsetAsync(cursor, 0, (size_t)n_nodes * 4, stream);
        hist_kernel<<<(n_edges + 255) / 256, 256, 0, stream>>>(dst, cursor, n_edges);
        scan1_kernel<<<NB, 256, 0, stream>>>(cursor, part, n_nodes);
        scan2_kernel<<<1, 512, 0, stream>>>(part, NB);
        scan3_kernel<<<NB, 256, 0, stream>>>(part, cursor, offs, n_nodes);
        scatter_kernel<<<(n_edges + 255) / 256, 256, 0, stream>>>(src, dst, cursor, esrc, n_edges);
        agg_kernel<<<(n_nodes + 3) / 4, 256, 0, stream>>>(esrc, offs, out, n_nodes);
    } else {
        zero_agg<<<3125, 256, 0, stream>>>(out, n_nodes);
        edge_agg<<<(n_edges + 7) / 8, 256, 0, stream>>>(src, dst, out, n_edges);
    }
}